// Round 1
// baseline (1011.471 us; speedup 1.0000x reference)
//
#include <hip/hip_runtime.h>
#include <math.h>

#define FDIM 64
#define RDIM 16
#define LN2F 0.69314718055994530942f

// Numerically stable softplus: max(x,0) + log1p(exp(-|x|))
__device__ __forceinline__ float sp(float x) {
    return fmaxf(x, 0.0f) + log1pf(__expf(-fabsf(x)));
}

// Kernel 1: per-atom. x = sp(emb)-ln2; v = sp(x@Wi+bi); y = sp(x@Wj+bj)
// One wave per atom, lane = output feature, weight columns in VGPRs.
__global__ __launch_bounds__(256) void k_atoms(
    const float* __restrict__ emb,
    const float* __restrict__ Wi, const float* __restrict__ bi,
    const float* __restrict__ Wj, const float* __restrict__ bj,
    float* __restrict__ v, float* __restrict__ y, int N)
{
    const int c = threadIdx.x & 63;
    const int g = threadIdx.x >> 6;
    float wi[FDIM], wj[FDIM];
#pragma unroll
    for (int k = 0; k < FDIM; ++k) {
        wi[k] = Wi[k * FDIM + c];
        wj[k] = Wj[k * FDIM + c];
    }
    const float bic = bi[c], bjc = bj[c];
    __shared__ __align__(16) float xs[4][FDIM];
    const int stride = gridDim.x * 4;
    for (int a0 = blockIdx.x * 4; a0 < N; a0 += stride) {
        const int a = a0 + g;
        float xv = 0.0f;
        if (a < N) xv = sp(emb[a * FDIM + c]) - LN2F;
        __syncthreads();
        xs[g][c] = xv;
        __syncthreads();
        if (a < N) {
            float acci = bic, accj = bjc;
            const float4* xr = (const float4*)xs[g];
#pragma unroll
            for (int k4 = 0; k4 < FDIM / 4; ++k4) {
                float4 xk = xr[k4];
                acci = fmaf(xk.x, wi[4 * k4 + 0], acci);
                accj = fmaf(xk.x, wj[4 * k4 + 0], accj);
                acci = fmaf(xk.y, wi[4 * k4 + 1], acci);
                accj = fmaf(xk.y, wj[4 * k4 + 1], accj);
                acci = fmaf(xk.z, wi[4 * k4 + 2], acci);
                accj = fmaf(xk.z, wj[4 * k4 + 2], accj);
                acci = fmaf(xk.w, wi[4 * k4 + 3], acci);
                accj = fmaf(xk.w, wj[4 * k4 + 3], accj);
            }
            v[a * FDIM + c] = sp(acci);
            y[a * FDIM + c] = sp(accj);
        }
    }
}

// Kernel 2: per-pair. msg = y[j] * (f @ G.T); atomicAdd into v[i].
// One wave per pair: j gather and i scatter are 256B contiguous per wave.
__global__ __launch_bounds__(256) void k_pairs(
    const int* __restrict__ pidx,    // [2, P]
    const float* __restrict__ f_ij,  // [P, R]
    const float* __restrict__ G,     // [F, R]
    const float* __restrict__ y,     // [N, F]
    float* __restrict__ v,           // [N, F]
    int P)
{
    const int c = threadIdx.x & 63;
    const int wave = (blockIdx.x << 2) | (threadIdx.x >> 6);
    const int nw = gridDim.x << 2;
    float4 gr[RDIM / 4];
    const float4* gp = (const float4*)(G + c * RDIM);
#pragma unroll
    for (int r4 = 0; r4 < RDIM / 4; ++r4) gr[r4] = gp[r4];
    const int* idx_i = pidx;
    const int* idx_j = pidx + P;
    const int per = (P + nw - 1) / nw;
    int p0 = wave * per;
    int p1 = p0 + per; if (p1 > P) p1 = P;
    for (int p = p0; p < p1; ++p) {
        const int i = idx_i[p];
        const int j = idx_j[p];
        const float4* fr = (const float4*)(f_ij + p * RDIM);
        float acc = 0.0f;
#pragma unroll
        for (int r4 = 0; r4 < RDIM / 4; ++r4) {
            float4 f4 = fr[r4];
            acc = fmaf(f4.x, gr[r4].x, acc);
            acc = fmaf(f4.y, gr[r4].y, acc);
            acc = fmaf(f4.z, gr[r4].z, acc);
            acc = fmaf(f4.w, gr[r4].w, acc);
        }
        atomicAdd(&v[i * FDIM + c], acc * y[j * FDIM + c]);
    }
}

// Kernel 3: one residual block: v += sp(v@W1+b1)@W2 + b2  (in-place on v)
__global__ __launch_bounds__(256) void k_res(
    const float* __restrict__ W1, const float* __restrict__ b1,
    const float* __restrict__ W2, const float* __restrict__ b2,
    float* __restrict__ v, int N)
{
    const int c = threadIdx.x & 63;
    const int g = threadIdx.x >> 6;
    float w1[FDIM], w2[FDIM];
#pragma unroll
    for (int k = 0; k < FDIM; ++k) {
        w1[k] = W1[k * FDIM + c];
        w2[k] = W2[k * FDIM + c];
    }
    const float b1c = b1[c], b2c = b2[c];
    __shared__ __align__(16) float vs[4][FDIM];
    __shared__ __align__(16) float hs[4][FDIM];
    const int stride = gridDim.x * 4;
    for (int a0 = blockIdx.x * 4; a0 < N; a0 += stride) {
        const int a = a0 + g;
        float vv = 0.0f;
        if (a < N) vv = v[a * FDIM + c];
        __syncthreads();
        vs[g][c] = vv;
        __syncthreads();
        float acc = b1c;
        {
            const float4* vr = (const float4*)vs[g];
#pragma unroll
            for (int k4 = 0; k4 < FDIM / 4; ++k4) {
                float4 xk = vr[k4];
                acc = fmaf(xk.x, w1[4 * k4 + 0], acc);
                acc = fmaf(xk.y, w1[4 * k4 + 1], acc);
                acc = fmaf(xk.z, w1[4 * k4 + 2], acc);
                acc = fmaf(xk.w, w1[4 * k4 + 3], acc);
            }
        }
        __syncthreads();
        hs[g][c] = sp(acc);
        __syncthreads();
        float acc2 = b2c;
        {
            const float4* hr = (const float4*)hs[g];
#pragma unroll
            for (int k4 = 0; k4 < FDIM / 4; ++k4) {
                float4 xk = hr[k4];
                acc2 = fmaf(xk.x, w2[4 * k4 + 0], acc2);
                acc2 = fmaf(xk.y, w2[4 * k4 + 1], acc2);
                acc2 = fmaf(xk.z, w2[4 * k4 + 2], acc2);
                acc2 = fmaf(xk.w, w2[4 * k4 + 3], acc2);
            }
        }
        if (a < N) v[a * FDIM + c] = vv + acc2;
    }
}

// Kernel 4: out = sp(v) @ Wv + bv  (in-place: v buffer IS d_out)
__global__ __launch_bounds__(256) void k_final(
    const float* __restrict__ Wv, const float* __restrict__ bv,
    float* __restrict__ v, int N)
{
    const int c = threadIdx.x & 63;
    const int g = threadIdx.x >> 6;
    float wv[FDIM];
#pragma unroll
    for (int k = 0; k < FDIM; ++k) wv[k] = Wv[k * FDIM + c];
    const float bvc = bv[c];
    __shared__ __align__(16) float vs[4][FDIM];
    const int stride = gridDim.x * 4;
    for (int a0 = blockIdx.x * 4; a0 < N; a0 += stride) {
        const int a = a0 + g;
        float vv = 0.0f;
        if (a < N) vv = sp(v[a * FDIM + c]);
        __syncthreads();
        vs[g][c] = vv;
        __syncthreads();
        float acc = bvc;
        const float4* vr = (const float4*)vs[g];
#pragma unroll
        for (int k4 = 0; k4 < FDIM / 4; ++k4) {
            float4 xk = vr[k4];
            acc = fmaf(xk.x, wv[4 * k4 + 0], acc);
            acc = fmaf(xk.y, wv[4 * k4 + 1], acc);
            acc = fmaf(xk.z, wv[4 * k4 + 2], acc);
            acc = fmaf(xk.w, wv[4 * k4 + 3], acc);
        }
        if (a < N) v[a * FDIM + c] = acc;
    }
}

extern "C" void kernel_launch(void* const* d_in, const int* in_sizes, int n_in,
                              void* d_out, int out_size, void* d_ws, size_t ws_size,
                              hipStream_t stream)
{
    const int*   pidx = (const int*)d_in[0];    // [2, P]
    const float* f_ij = (const float*)d_in[1];  // [P, 1, R]
    // d_in[2] = d_ij, unused by the reference
    const float* emb  = (const float*)d_in[3];  // [N, F]
    const float* G    = (const float*)d_in[4];  // [F, R]
    const float* Wi   = (const float*)d_in[5];
    const float* bi   = (const float*)d_in[6];
    const float* Wj   = (const float*)d_in[7];
    const float* bj   = (const float*)d_in[8];
    const float* rW1  = (const float*)d_in[9];  // [3, F, F]
    const float* rb1  = (const float*)d_in[10]; // [3, F]
    const float* rW2  = (const float*)d_in[11];
    const float* rb2  = (const float*)d_in[12];
    const float* Wv   = (const float*)d_in[13];
    const float* bv   = (const float*)d_in[14];

    const int P = in_sizes[0] / 2;
    const int N = in_sizes[3] / FDIM;

    float* v = (float*)d_out;  // [N, F] accumulator; becomes the output
    float* y = (float*)d_ws;   // [N, F] precomputed sp(x@Wj+bj)

    dim3 blk(256);
    k_atoms<<<2048, blk, 0, stream>>>(emb, Wi, bi, Wj, bj, v, y, N);
    k_pairs<<<2048, blk, 0, stream>>>(pidx, f_ij, G, y, v, P);
    for (int l = 0; l < 3; ++l) {
        k_res<<<2048, blk, 0, stream>>>(rW1 + l * FDIM * FDIM, rb1 + l * FDIM,
                                        rW2 + l * FDIM * FDIM, rb2 + l * FDIM, v, N);
    }
    k_final<<<2048, blk, 0, stream>>>(Wv, bv, v, N);
}